// Round 3
// baseline (2057.698 us; speedup 1.0000x reference)
//
#include <hip/hip_runtime.h>

// Problem constants
#define NPOS   158   // 64 query + 94 doc token positions per batch
#define NCH    32    // chains (windows) per block
#define EPITCH 136   // shorts per staged emb row (128 + 8 pad)

// workspace layout
#define WQ_SHORTS (2*8*32*2*64*8)          // 524288: [dir][wv8][sl32][n2][lane64][j8]
#define KP_SHORTS (2*64*4*512)             // k packed for xzgemm (unchanged layout)
#define XZ_HALFS  ((size_t)2*128*158*1024)
#define OFF_KP    ((size_t)WQ_SHORTS*2)                 // 1,048,576
#define OFF_XZ    (OFF_KP + (size_t)KP_SHORTS*2)        // 1,572,864
#define OFF_HOUT  (OFF_XZ + XZ_HALFS*2)                 // 84,410,368

typedef __attribute__((ext_vector_type(8))) short    short8;
typedef __attribute__((ext_vector_type(4))) short    short4v;
typedef __attribute__((ext_vector_type(4))) float    float4v;
typedef __attribute__((ext_vector_type(8))) _Float16 half8;

__device__ __forceinline__ unsigned short f2bf(float x){
  unsigned int u = __builtin_bit_cast(unsigned int, x);
  u += 0x7FFFu + ((u >> 16) & 1u);           // round-to-nearest-even
  return (unsigned short)(u >> 16);
}
__device__ __forceinline__ float fsig(float x){
  return 1.0f/(1.0f + __expf(-x));
}
__device__ __forceinline__ float ftanh(float x){
  float ax = fabsf(x);
  float e  = __expf(-2.0f*ax);
  float r  = (1.0f - e)/(1.0f + e);
  return (x < 0.0f) ? -r : r;
}

// async global->LDS DMA, 16B per lane (lds dst = wave-uniform base + lane*16)
__device__ __forceinline__ void dma16(const void* g, void* l){
  __builtin_amdgcn_global_load_lds((const __attribute__((address_space(1))) void*)g,
                                   (__attribute__((address_space(3))) void*)l, 16, 0, 0);
}

// ---------------------------------------------------------------------------
// Pack rk into per-wave DMA slice order:
//   wq[dir][wv 8][sl 32][n 2][lane 64][j 8], sl = ks*4+g, nt = g*16+wv*2+n,
//   element = rk[k = ks*32+(lane>>4)*8+j][col = nt*16+(lane&15)].
// Also pack k (for xzgemm) as before: kp[dir][nt 64][ks 4][lane 64][j 8].
// ---------------------------------------------------------------------------
__global__ void prepack(const float* __restrict__ kf, const float* __restrict__ rkf,
                        const float* __restrict__ kb, const float* __restrict__ rkb,
                        unsigned short* __restrict__ wq, unsigned short* __restrict__ kp){
  int idx = blockIdx.x*256 + threadIdx.x;
  if (idx < WQ_SHORTS){
    int j = idx & 7, lane = (idx>>3)&63, n = (idx>>9)&1, sl = (idx>>10)&31,
        wv = (idx>>15)&7, d = (idx>>18)&1;
    int ks = sl>>2, g = sl&3;
    int nt  = g*16 + wv*2 + n;
    int k   = ks*32 + (lane>>4)*8 + j;
    int col = nt*16 + (lane&15);
    const float* RK = d ? rkb : rkf;
    wq[idx] = f2bf(RK[k*1024 + col]);
  } else {
    int i2 = idx - WQ_SHORTS;
    if (i2 < KP_SHORTS){
      int j = i2 & 7, lane = (i2>>3)&63, ks = (i2>>9)&3, nt = (i2>>11)&63, d = i2>>17;
      const float* K = d ? kb : kf;
      int k   = ks*32 + (lane>>4)*8 + j;
      int col = nt*16 + (lane&15);
      kp[i2] = f2bf(K[k*1024 + col]);
    }
  }
}

// ---------------------------------------------------------------------------
// xz[dir][bat][pos][1024] (fp16, wave-permuted inner layout) = emb @ k + bias.
// Inner layout: [pos][wv 8][lc 16][n 8], n = gate*2 + tj.
// ---------------------------------------------------------------------------
__launch_bounds__(512)
__global__ void xzgemm(const int* __restrict__ inputs, const float* __restrict__ emb,
                       const unsigned short* __restrict__ kpack,
                       const float* __restrict__ b_f, const float* __restrict__ b_b,
                       _Float16* __restrict__ xz){
  __shared__ int tokp[32];
  __shared__ __align__(16) short e_lds[32*EPITCH];
  const int bid = blockIdx.x;
  const int pt  = bid % 5;
  const int bd  = bid / 5;
  const int bat = bd & 127, dir = bd >> 7;
  const int tid = threadIdx.x, lane = tid & 63, wv = tid >> 6;
  const int lc  = lane & 15, q = lane >> 4;

  for (int i = tid; i < 32*EPITCH; i += 512) e_lds[i] = 0;
  if (tid < 32){
    int p = pt*32 + tid;
    tokp[tid] = (p < NPOS) ? inputs[bat*NPOS + p] : 0;
  }
  __syncthreads();
  for (int idx = tid; idx < 32*32; idx += 512){
    int i = idx >> 5, c4 = (idx & 31) << 2;
    int p = pt*32 + i;
    if (p < NPOS){
      float4v v = *(const float4v*)(emb + (long)tokp[i]*128 + c4);
      short4v s;
      s[0]=(short)f2bf(v[0]); s[1]=(short)f2bf(v[1]);
      s[2]=(short)f2bf(v[2]); s[3]=(short)f2bf(v[3]);
      *(short4v*)&e_lds[i*EPITCH + c4] = s;
    }
  }
  __syncthreads();

  const float* bias = dir ? b_b : b_f;
  float4v acc[2][8];
  #pragma unroll
  for (int g = 0; g < 4; ++g)
    #pragma unroll
    for (int tj = 0; tj < 2; ++tj){
      float bv = bias[g*256 + wv*32 + tj*16 + lc];
      acc[0][g*2+tj] = (float4v){bv,bv,bv,bv};
      acc[1][g*2+tj] = acc[0][g*2+tj];
    }

  const short8* KP = (const short8*)kpack + (long)dir*64*4*64;
  #pragma unroll
  for (int ks = 0; ks < 4; ++ks){
    short8 a0 = *(const short8*)&e_lds[lc*EPITCH + ks*32 + q*8];
    short8 a1 = *(const short8*)&e_lds[(16+lc)*EPITCH + ks*32 + q*8];
    #pragma unroll
    for (int n = 0; n < 8; ++n){
      int g = n >> 1, tj = n & 1;
      int nt = g*16 + wv*2 + tj;
      short8 b = KP[(nt*4 + ks)*64 + lane];
      acc[0][n] = __builtin_amdgcn_mfma_f32_16x16x32_bf16(a0, b, acc[0][n], 0, 0, 0);
      acc[1][n] = __builtin_amdgcn_mfma_f32_16x16x32_bf16(a1, b, acc[1][n], 0, 0, 0);
    }
  }

  _Float16* xzb = xz + ((long)(dir*128 + bat))*NPOS*1024;
  #pragma unroll
  for (int mt = 0; mt < 2; ++mt)
    #pragma unroll
    for (int r = 0; r < 4; ++r){
      int row = mt*16 + q*4 + r;
      int p = pt*32 + row;
      if (p < NPOS){
        half8 hv;
        #pragma unroll
        for (int n = 0; n < 8; ++n) hv[n] = (_Float16)acc[mt][n][r];
        __builtin_nontemporal_store(hv, (half8*)(xzb + (long)p*1024 + wv*128 + lc*8));
      }
    }
}

// ---------------------------------------------------------------------------
// Recurrent kernel: block = (batch, dir), 32 chains, 64 steps, K=256.
// Weights stream via per-wave async global_load_lds ring (3 bufs x 2 KB,
// prefetch distance 2, s_waitcnt vmcnt ring discipline) -> zero VGPR cost for
// in-flight loads. h single-buffered in LDS with XOR chunk swizzle (64 KB total
// LDS). xz loads issued mid slice-loop (ks==6), consumed after barrier.
// ---------------------------------------------------------------------------
__launch_bounds__(512)
__global__ void lstm_rec(const int* __restrict__ inputs, const _Float16* __restrict__ xz,
                         const unsigned short* __restrict__ wq,
                         const float* __restrict__ wci_f, const float* __restrict__ wcf_f,
                         const float* __restrict__ wco_f,
                         const float* __restrict__ wci_b, const float* __restrict__ wcf_b,
                         const float* __restrict__ wco_b,
                         float* __restrict__ h_out)
{
  // 16384 + 49152 = 65536 B exactly
  __shared__ __align__(16) short h_lds[32*256];        // swizzled: chunk u of row m at m*256 + (u^m)*8
  __shared__ __align__(16) short wbuf[8][3][1024];     // per-wave ring: 3 bufs x 2 KB

  const int tid  = threadIdx.x;
  const int lane = tid & 63;
  const int wv   = tid >> 6;
  const int lc   = lane & 15;
  const int q    = lane >> 4;
  const int bat  = blockIdx.x & 127;
  const int dir  = blockIdx.x >> 7;

  // ---- mask build (overlay in wbuf before DMA starts) + h zero ----
  unsigned* mtmp = (unsigned*)&wbuf[0][0][0];
  if (tid < 5) mtmp[tid] = 0;
  for (int i = tid; i < 32*256; i += 512) h_lds[i] = 0;
  __syncthreads();
  if (tid < NPOS){
    if (inputs[bat*NPOS + tid] != 0) atomicOr(&mtmp[tid>>5], 1u << (tid & 31));
  }
  __syncthreads();
  const unsigned mw0 = mtmp[0], mw1 = mtmp[1], mw2 = mtmp[2], mw3 = mtmp[3], mw4 = mtmp[4];
  __syncthreads();   // overlay read complete before DMA overwrites wbuf

  const float* wci = dir ? wci_b : wci_f;
  const float* wcf = dir ? wcf_b : wcf_f;
  const float* wco = dir ? wco_b : wco_f;
  float wcir[2], wcfr[2], wcor[2];
  #pragma unroll
  for (int tj = 0; tj < 2; ++tj){
    int j = wv*32 + tj*16 + lc;
    wcir[tj] = wci[j]; wcfr[tj] = wcf[j]; wcor[tj] = wco[j];
  }

  float hreg[2][4][2], creg[2][4][2];
  #pragma unroll
  for (int mt = 0; mt < 2; ++mt)
    #pragma unroll
    for (int r = 0; r < 4; ++r)
      #pragma unroll
      for (int tj = 0; tj < 2; ++tj){ hreg[mt][r][tj] = 0.f; creg[mt][r][tj] = 0.f; }

  // per-(dir,wave) weight region: 32 slices x 2048 B; per-lane src includes lane*16
  const char* wsrc = (const char*)wq + ((size_t)(dir*8 + wv))*65536 + (size_t)lane*16;
  const _Float16* xzb = xz + ((long)(dir*128 + bat))*NPOS*1024 + wv*128 + lc*8;

  // DMA prologue: slices 0,1 -> bufs 0,1
  dma16(wsrc + 0*2048,        &wbuf[wv][0][0]);
  dma16(wsrc + 0*2048 + 1024, &wbuf[wv][0][512]);
  dma16(wsrc + 1*2048,        &wbuf[wv][1][0]);
  dma16(wsrc + 1*2048 + 1024, &wbuf[wv][1][512]);
  int bph = 0;   // buffer index of slice 0 of current step

  const int m0 = lc, m1 = 16 + lc;

  for (int s = 0; s < 64; ++s){
    const int t = dir ? (63 - s) : s;

    float4v acc[2][8];
    #pragma unroll
    for (int mt = 0; mt < 2; ++mt)
      #pragma unroll
      for (int n = 0; n < 8; ++n) acc[mt][n] = (float4v){0.f,0.f,0.f,0.f};

    half8 xzr[2][4];   // loaded at ks==6, consumed in gate phase

    #pragma unroll
    for (int ks = 0; ks < 8; ++ks){
      if (ks == 6){
        // issue xz loads for this step; latency hides under slices 24..31
        #pragma unroll
        for (int mt = 0; mt < 2; ++mt)
          #pragma unroll
          for (int r = 0; r < 4; ++r){
            int m = mt*16 + q*4 + r;
            int p = (m == 0) ? t : 63 + m + t;
            xzr[mt][r] = __builtin_nontemporal_load((const half8*)(xzb + (long)p*1024));
          }
      }
      short8 a0 = *(const short8*)&h_lds[m0*256 + ((4*ks + q) ^ m0)*8];
      short8 a1 = *(const short8*)&h_lds[m1*256 + ((4*ks + q) ^ m1)*8];
      #pragma unroll
      for (int g = 0; g < 4; ++g){
        const int cc = ks*4 + g;
        // ring discipline: allow next slice (2 DMAs) in flight; after xz issue,
        // also allow the 8 xz loads (newest) to remain outstanding
        if (cc >= 24) asm volatile("s_waitcnt vmcnt(10)" ::: "memory");
        else          asm volatile("s_waitcnt vmcnt(2)"  ::: "memory");
        int buf = (unsigned)(bph + cc) % 3u;
        const short* wb = &wbuf[wv][buf][0];
        short8 b0 = *(const short8*)(wb + lane*8);
        short8 b1 = *(const short8*)(wb + 512 + lane*8);
        acc[0][g*2+0] = __builtin_amdgcn_mfma_f32_16x16x32_bf16(a0, b0, acc[0][g*2+0], 0, 0, 0);
        acc[1][g*2+0] = __builtin_amdgcn_mfma_f32_16x16x32_bf16(a1, b0, acc[1][g*2+0], 0, 0, 0);
        acc[0][g*2+1] = __builtin_amdgcn_mfma_f32_16x16x32_bf16(a0, b1, acc[0][g*2+1], 0, 0, 0);
        acc[1][g*2+1] = __builtin_amdgcn_mfma_f32_16x16x32_bf16(a1, b1, acc[1][g*2+1], 0, 0, 0);
        // prefetch slice cc+2 (same weights every step: index mod 32)
        int nsl = (cc + 2) & 31;
        int nb  = (unsigned)(bph + cc + 2) % 3u;
        dma16(wsrc + nsl*2048,        &wbuf[wv][nb][0]);
        dma16(wsrc + nsl*2048 + 1024, &wbuf[wv][nb][512]);
      }
    }

    __syncthreads();   // all waves done reading h_lds (and xz/DMAs drained)

    // gates: C/D layout row = q*4+r (chain), col = lc
    #pragma unroll
    for (int mt = 0; mt < 2; ++mt){
      #pragma unroll
      for (int r = 0; r < 4; ++r){
        int m = mt*16 + q*4 + r;
        int p = (m == 0) ? t : 63 + m + t;
        unsigned mwsel = mw0;
        int widx = p >> 5;
        mwsel = (widx == 1) ? mw1 : mwsel;
        mwsel = (widx == 2) ? mw2 : mwsel;
        mwsel = (widx == 3) ? mw3 : mwsel;
        mwsel = (widx == 4) ? mw4 : mwsel;
        bool msk = (mwsel >> (p & 31)) & 1u;
        #pragma unroll
        for (int tj = 0; tj < 2; ++tj){
          float zi = acc[mt][0+tj][r] + (float)xzr[mt][r][0+tj];
          float zf = acc[mt][2+tj][r] + (float)xzr[mt][r][2+tj];
          float zc = acc[mt][4+tj][r] + (float)xzr[mt][r][4+tj];
          float zo = acc[mt][6+tj][r] + (float)xzr[mt][r][6+tj];
          float c0 = creg[mt][r][tj];
          float ig = fsig(zi + c0*wcir[tj]);
          float fg = fsig(zf + c0*wcfr[tj]);
          float cn = fg*c0 + ig*ftanh(zc);
          float og = fsig(zo + cn*wcor[tj]);
          float hn = og*ftanh(cn);
          float hv = msk ? hn : hreg[mt][r][tj];
          float cv = msk ? cn : c0;
          hreg[mt][r][tj] = hv;
          creg[mt][r][tj] = cv;
          // swizzled write: j = wv*32+tj*16+lc, chunk u = j>>3, phys = u^m
          int u = wv*4 + tj*2 + (lc >> 3);
          h_lds[m*256 + (u ^ m)*8 + (lc & 7)] = (short)f2bf(hv);
        }
      }
    }
    __syncthreads();   // h writes visible before next step's MFMA reads
    bph = (unsigned)(bph + 2) % 3u;   // 32 mod 3
  }

  #pragma unroll
  for (int mt = 0; mt < 2; ++mt)
    #pragma unroll
    for (int r = 0; r < 4; ++r){
      int m = mt*16 + q*4 + r;
      #pragma unroll
      for (int tj = 0; tj < 2; ++tj){
        int j = wv*32 + tj*16 + lc;
        __builtin_nontemporal_store(hreg[mt][r][tj],
            &h_out[(((long)dir*128 + bat)*32 + m)*256 + j]);
      }
    }
}

// ---------------------------------------------------------------------------
// h_avg = 0.5(h_f + h_b); cos = |q.d|/(|q||d|); softmax over 31 docs.
// ---------------------------------------------------------------------------
__global__ void finalize(const float* __restrict__ h_out, float* __restrict__ out){
  __shared__ float hav[32*256];
  __shared__ float dotl[32], sql[32];
  const int bat = blockIdx.x;
  const int tid = threadIdx.x;
  const float* hf = h_out + (long)bat*8192;
  const float* hb = h_out + (long)(128 + bat)*8192;
  for (int i = tid; i < 8192; i += 256) hav[i] = 0.5f*(hf[i] + hb[i]);
  __syncthreads();
  const int lane = tid & 63, wv = tid >> 6;
  for (int n = wv; n < 32; n += 4){
    float s1 = 0.f, s2 = 0.f;
    for (int j = lane; j < 256; j += 64){
      float a  = hav[n*256 + j];
      float qv = hav[j];
      s1 += a*qv; s2 += a*a;
    }
    #pragma unroll
    for (int off = 32; off; off >>= 1){
      s1 += __shfl_down(s1, off);
      s2 += __shfl_down(s2, off);
    }
    if (lane == 0){ dotl[n] = s1; sql[n] = s2; }
  }
  __syncthreads();
  if (wv == 0){
    float cosv = -1e30f;
    if (lane < 31)
      cosv = fabsf(dotl[lane+1]) / (sqrtf(sql[0]) * sqrtf(sql[lane+1]));
    float mx = cosv;
    #pragma unroll
    for (int off = 32; off; off >>= 1) mx = fmaxf(mx, __shfl_xor(mx, off));
    float e = (lane < 31) ? __expf(cosv - mx) : 0.f;
    float sum = e;
    #pragma unroll
    for (int off = 32; off; off >>= 1) sum += __shfl_xor(sum, off);
    if (lane < 31) out[bat*31 + lane] = e / sum;
  }
}

extern "C" void kernel_launch(void* const* d_in, const int* in_sizes, int n_in,
                              void* d_out, int out_size, void* d_ws, size_t ws_size,
                              hipStream_t stream) {
  const int*   inputs = (const int*)  d_in[0];
  const float* emb    = (const float*)d_in[1];
  const float* k_f    = (const float*)d_in[2];
  const float* rk_f   = (const float*)d_in[3];
  const float* b_f    = (const float*)d_in[4];
  const float* wci_f  = (const float*)d_in[5];
  const float* wcf_f  = (const float*)d_in[6];
  const float* wco_f  = (const float*)d_in[7];
  const float* k_b    = (const float*)d_in[8];
  const float* rk_b   = (const float*)d_in[9];
  const float* b_b    = (const float*)d_in[10];
  const float* wci_b  = (const float*)d_in[11];
  const float* wcf_b  = (const float*)d_in[12];
  const float* wco_b  = (const float*)d_in[13];

  unsigned short* wqp  = (unsigned short*)d_ws;
  unsigned short* kp   = (unsigned short*)((char*)d_ws + OFF_KP);
  _Float16*       xzp  = (_Float16*)     ((char*)d_ws + OFF_XZ);
  float*          hout = (float*)        ((char*)d_ws + OFF_HOUT);

  prepack<<<(WQ_SHORTS + KP_SHORTS)/256, 256, 0, stream>>>(k_f, rk_f, k_b, rk_b, wqp, kp);
  xzgemm <<<128*2*5, 512, 0, stream>>>(inputs, emb, kp, b_f, b_b, xzp);
  lstm_rec<<<256, 512, 0, stream>>>(inputs, xzp, wqp,
                                    wci_f, wcf_f, wco_f,
                                    wci_b, wcf_b, wco_b, hout);
  finalize<<<128, 256, 0, stream>>>(hout, (float*)d_out);
}

// Round 4
// 1630.321 us; speedup vs baseline: 1.2621x; 1.2621x over previous
//
#include <hip/hip_runtime.h>

// Problem constants
#define NPOS   158   // 64 query + 94 doc token positions per batch
#define NCH    32    // chains (windows) per block
#define EPITCH 136   // shorts per staged emb row (128 + 8 pad)

// workspace layout
#define RKP_SHORTS (2*64*8*512)            // rk packed: [dir][nt64][ks8][lane64][j8]
#define KP_SHORTS  (2*64*4*512)            // k  packed: [dir][nt64][ks4][lane64][j8]
#define XZ_HALFS   ((size_t)2*128*158*1024)
#define OFF_KP     ((size_t)RKP_SHORTS*2)                 // 1,048,576
#define OFF_XZ     (OFF_KP + (size_t)KP_SHORTS*2)         // 1,572,864
#define OFF_HOUT   (OFF_XZ + XZ_HALFS*2)                  // 84,410,368

typedef __attribute__((ext_vector_type(8))) short    short8;
typedef __attribute__((ext_vector_type(4))) short    short4v;
typedef __attribute__((ext_vector_type(4))) float    float4v;
typedef __attribute__((ext_vector_type(8))) _Float16 half8;

__device__ __forceinline__ unsigned short f2bf(float x){
  unsigned int u = __builtin_bit_cast(unsigned int, x);
  u += 0x7FFFu + ((u >> 16) & 1u);           // round-to-nearest-even
  return (unsigned short)(u >> 16);
}
__device__ __forceinline__ float fsig(float x){
  return 1.0f/(1.0f + __expf(-x));
}
__device__ __forceinline__ float ftanh(float x){
  float ax = fabsf(x);
  float e  = __expf(-2.0f*ax);
  float r  = (1.0f - e)/(1.0f + e);
  return (x < 0.0f) ? -r : r;
}

// ---------------------------------------------------------------------------
// Pack rk (256x1024) and k (128x1024) per dir into MFMA B-fragment lane order:
// element j of lane l for tile (nt,ks) = W[k = ks*32+(l>>4)*8+j][col = nt*16+(l&15)].
// ---------------------------------------------------------------------------
__global__ void prepack(const float* __restrict__ kf, const float* __restrict__ rkf,
                        const float* __restrict__ kb, const float* __restrict__ rkb,
                        unsigned short* __restrict__ rkp, unsigned short* __restrict__ kp){
  int idx = blockIdx.x*256 + threadIdx.x;
  if (idx < RKP_SHORTS){
    int j = idx & 7, lane = (idx>>3)&63, ks = (idx>>9)&7, nt = (idx>>12)&63, d = idx>>18;
    const float* RK = d ? rkb : rkf;
    int k   = ks*32 + (lane>>4)*8 + j;
    int col = nt*16 + (lane&15);
    rkp[idx] = f2bf(RK[k*1024 + col]);
  } else {
    int i2 = idx - RKP_SHORTS;
    if (i2 < KP_SHORTS){
      int j = i2 & 7, lane = (i2>>3)&63, ks = (i2>>9)&3, nt = (i2>>11)&63, d = i2>>17;
      const float* K = d ? kb : kf;
      int k   = ks*32 + (lane>>4)*8 + j;
      int col = nt*16 + (lane&15);
      kp[i2] = f2bf(K[k*1024 + col]);
    }
  }
}

// ---------------------------------------------------------------------------
// xz[dir][bat][pos][1024] (fp16, wave-permuted inner layout) = emb @ k + bias.
// Inner layout: [pos][wv 8][lc 16][n 8], n = gate*2 + tj.
// ---------------------------------------------------------------------------
__launch_bounds__(512)
__global__ void xzgemm(const int* __restrict__ inputs, const float* __restrict__ emb,
                       const unsigned short* __restrict__ kpack,
                       const float* __restrict__ b_f, const float* __restrict__ b_b,
                       _Float16* __restrict__ xz){
  __shared__ int tokp[32];
  __shared__ __align__(16) short e_lds[32*EPITCH];
  const int bid = blockIdx.x;
  const int pt  = bid % 5;
  const int bd  = bid / 5;
  const int bat = bd & 127, dir = bd >> 7;
  const int tid = threadIdx.x, lane = tid & 63, wv = tid >> 6;
  const int lc  = lane & 15, q = lane >> 4;

  for (int i = tid; i < 32*EPITCH; i += 512) e_lds[i] = 0;
  if (tid < 32){
    int p = pt*32 + tid;
    tokp[tid] = (p < NPOS) ? inputs[bat*NPOS + p] : 0;
  }
  __syncthreads();
  for (int idx = tid; idx < 32*32; idx += 512){
    int i = idx >> 5, c4 = (idx & 31) << 2;
    int p = pt*32 + i;
    if (p < NPOS){
      float4v v = *(const float4v*)(emb + (long)tokp[i]*128 + c4);
      short4v s;
      s[0]=(short)f2bf(v[0]); s[1]=(short)f2bf(v[1]);
      s[2]=(short)f2bf(v[2]); s[3]=(short)f2bf(v[3]);
      *(short4v*)&e_lds[i*EPITCH + c4] = s;
    }
  }
  __syncthreads();

  const float* bias = dir ? b_b : b_f;
  float4v acc[2][8];
  #pragma unroll
  for (int g = 0; g < 4; ++g)
    #pragma unroll
    for (int tj = 0; tj < 2; ++tj){
      float bv = bias[g*256 + wv*32 + tj*16 + lc];
      acc[0][g*2+tj] = (float4v){bv,bv,bv,bv};
      acc[1][g*2+tj] = acc[0][g*2+tj];
    }

  const short8* KP = (const short8*)kpack + (long)dir*64*4*64;
  #pragma unroll
  for (int ks = 0; ks < 4; ++ks){
    short8 a0 = *(const short8*)&e_lds[lc*EPITCH + ks*32 + q*8];
    short8 a1 = *(const short8*)&e_lds[(16+lc)*EPITCH + ks*32 + q*8];
    #pragma unroll
    for (int n = 0; n < 8; ++n){
      int g = n >> 1, tj = n & 1;
      int nt = g*16 + wv*2 + tj;
      short8 b = KP[(nt*4 + ks)*64 + lane];
      acc[0][n] = __builtin_amdgcn_mfma_f32_16x16x32_bf16(a0, b, acc[0][n], 0, 0, 0);
      acc[1][n] = __builtin_amdgcn_mfma_f32_16x16x32_bf16(a1, b, acc[1][n], 0, 0, 0);
    }
  }

  _Float16* xzb = xz + ((long)(dir*128 + bat))*NPOS*1024;
  #pragma unroll
  for (int mt = 0; mt < 2; ++mt)
    #pragma unroll
    for (int r = 0; r < 4; ++r){
      int row = mt*16 + q*4 + r;
      int p = pt*32 + row;
      if (p < NPOS){
        half8 hv;
        #pragma unroll
        for (int n = 0; n < 8; ++n) hv[n] = (_Float16)acc[mt][n][r];
        __builtin_nontemporal_store(hv, (half8*)(xzb + (long)p*1024 + wv*128 + lc*8));
      }
    }
}

// ---------------------------------------------------------------------------
// Recurrent kernel: block = (batch, dir), 32 chains, 64 steps, K=256.
// B-fragments stream L2->VGPR through a STATIC 3-slot register ring; the
// ring's tail refills (ks=5..7) prefetch the NEXT step's slices 0..2 and stay
// in flight across the barrier, because the step barrier is a raw
// "s_waitcnt lgkmcnt(0); s_barrier" (LDS-visibility only - no vmcnt drain;
// in-flight global loads target wave-private registers, so this is safe).
// h double-buffered in LDS with XOR chunk swizzle (conflict-free), ONE
// barrier per step. amdgpu_waves_per_eu(2,2) tells the compiler 1 block/CU
// is the ceiling so it may use the full 256-VGPR budget for the ring.
// ---------------------------------------------------------------------------
__global__ __attribute__((amdgpu_flat_work_group_size(512,512), amdgpu_waves_per_eu(2,2)))
void lstm_rec(const int* __restrict__ inputs, const _Float16* __restrict__ xz,
              const unsigned short* __restrict__ rkpack,
              const float* __restrict__ wci_f, const float* __restrict__ wcf_f,
              const float* __restrict__ wco_f,
              const float* __restrict__ wci_b, const float* __restrict__ wcf_b,
              const float* __restrict__ wco_b,
              float* __restrict__ h_out)
{
  __shared__ __align__(16) short h_lds[2][32*256];   // swizzled: chunk u of row m at m*256+(u^m)*8
  __shared__ unsigned marr[5];

  const int tid  = threadIdx.x;
  const int lane = tid & 63;
  const int wv   = tid >> 6;
  const int lc   = lane & 15;
  const int q    = lane >> 4;
  const int bat  = blockIdx.x & 127;
  const int dir  = blockIdx.x >> 7;

  if (tid < 5) marr[tid] = 0;
  for (int i = tid; i < 32*256; i += 512) h_lds[0][i] = 0;
  __syncthreads();
  if (tid < NPOS){
    if (inputs[bat*NPOS + tid] != 0) atomicOr(&marr[tid>>5], 1u << (tid & 31));
  }
  __syncthreads();
  const unsigned mw0 = marr[0], mw1 = marr[1], mw2 = marr[2], mw3 = marr[3], mw4 = marr[4];

  const float* wci = dir ? wci_b : wci_f;
  const float* wcf = dir ? wcf_b : wcf_f;
  const float* wco = dir ? wco_b : wco_f;
  float wcir[2], wcfr[2], wcor[2];
  #pragma unroll
  for (int tj = 0; tj < 2; ++tj){
    int j = wv*32 + tj*16 + lc;
    wcir[tj] = wci[j]; wcfr[tj] = wcf[j]; wcor[tj] = wco[j];
  }

  float hreg[2][4][2], creg[2][4][2];
  #pragma unroll
  for (int mt = 0; mt < 2; ++mt)
    #pragma unroll
    for (int r = 0; r < 4; ++r)
      #pragma unroll
      for (int tj = 0; tj < 2; ++tj){ hreg[mt][r][tj] = 0.f; creg[mt][r][tj] = 0.f; }

  const short8*   RK  = (const short8*)rkpack + (long)dir*64*8*64;
  const _Float16* xzb = xz + ((long)(dir*128 + bat))*NPOS*1024 + wv*128 + lc*8;

  // ---- static register ring: preload slices 0,1,2 into slots 0,1,2 ----
  short8 bb[3][8];
  #pragma unroll
  for (int sl = 0; sl < 3; ++sl)
    #pragma unroll
    for (int f = 0; f < 8; ++f){
      int g = f >> 1, n = f & 1, nt = g*16 + wv*2 + n;
      bb[sl][f] = RK[(nt*8 + sl)*64 + lane];
    }

  const int m0 = lc, m1 = 16 + lc;

  for (int s = 0; s < 64; ++s){
    const int t = dir ? (63 - s) : s;
    const short* hr = &h_lds[s & 1][0];
    short*       hw = &h_lds[(s & 1) ^ 1][0];

    float4v acc[2][8];
    #pragma unroll
    for (int mt = 0; mt < 2; ++mt)
      #pragma unroll
      for (int n = 0; n < 8; ++n) acc[mt][n] = (float4v){0.f,0.f,0.f,0.f};

    half8 xzr[2][4];

    // refill table: ks=0..4 -> slice ks+3 (this step); ks=5,6,7 -> NEXT step's
    // slices 2,0,1 so slot sl holds slice sl when the next step begins.
    #pragma unroll
    for (int ks = 0; ks < 8; ++ks){
      const int slot = ks % 3;
      if (ks == 5){
        // prefetch this step's xz (consumed in the gate phase below)
        #pragma unroll
        for (int mt = 0; mt < 2; ++mt)
          #pragma unroll
          for (int r = 0; r < 4; ++r){
            int m = mt*16 + q*4 + r;
            int p = (m == 0) ? t : 63 + m + t;
            xzr[mt][r] = __builtin_nontemporal_load((const half8*)(xzb + (long)p*1024));
          }
      }
      short8 a0 = *(const short8*)&hr[m0*256 + ((4*ks + q) ^ m0)*8];
      short8 a1 = *(const short8*)&hr[m1*256 + ((4*ks + q) ^ m1)*8];
      #pragma unroll
      for (int f = 0; f < 8; ++f){
        acc[0][f] = __builtin_amdgcn_mfma_f32_16x16x32_bf16(a0, bb[slot][f], acc[0][f], 0, 0, 0);
        acc[1][f] = __builtin_amdgcn_mfma_f32_16x16x32_bf16(a1, bb[slot][f], acc[1][f], 0, 0, 0);
      }
      const int rsl = (ks < 5) ? (ks + 3) : ((ks == 5) ? 2 : (ks == 6 ? 0 : 1));
      #pragma unroll
      for (int f = 0; f < 8; ++f){
        int g = f >> 1, n = f & 1, nt = g*16 + wv*2 + n;
        bb[slot][f] = RK[(nt*8 + rsl)*64 + lane];
      }
    }

    // gates: C/D layout row = q*4+r (chain), col = lc
    #pragma unroll
    for (int mt = 0; mt < 2; ++mt){
      #pragma unroll
      for (int r = 0; r < 4; ++r){
        int m = mt*16 + q*4 + r;
        int p = (m == 0) ? t : 63 + m + t;
        unsigned mwsel = mw0;
        int widx = p >> 5;
        mwsel = (widx == 1) ? mw1 : mwsel;
        mwsel = (widx == 2) ? mw2 : mwsel;
        mwsel = (widx == 3) ? mw3 : mwsel;
        mwsel = (widx == 4) ? mw4 : mwsel;
        bool msk = (mwsel >> (p & 31)) & 1u;
        #pragma unroll
        for (int tj = 0; tj < 2; ++tj){
          float zi = acc[mt][0+tj][r] + (float)xzr[mt][r][0+tj];
          float zf = acc[mt][2+tj][r] + (float)xzr[mt][r][2+tj];
          float zc = acc[mt][4+tj][r] + (float)xzr[mt][r][4+tj];
          float zo = acc[mt][6+tj][r] + (float)xzr[mt][r][6+tj];
          float c0 = creg[mt][r][tj];
          float ig = fsig(zi + c0*wcir[tj]);
          float fg = fsig(zf + c0*wcfr[tj]);
          float cn = fg*c0 + ig*ftanh(zc);
          float og = fsig(zo + cn*wcor[tj]);
          float hn = og*ftanh(cn);
          float hv = msk ? hn : hreg[mt][r][tj];
          float cv = msk ? cn : c0;
          hreg[mt][r][tj] = hv;
          creg[mt][r][tj] = cv;
          int u = wv*4 + tj*2 + (lc >> 3);
          hw[m*256 + (u ^ m)*8 + (lc & 7)] = (short)f2bf(hv);
        }
      }
    }
    // LDS-only barrier: ds_writes drained + workgroup sync, but in-flight
    // GLOBAL loads (next step's weight slices, wave-private registers) are
    // deliberately NOT drained -> cross-step pipeline survives.
    asm volatile("s_waitcnt lgkmcnt(0)\n\ts_barrier" ::: "memory");
  }

  #pragma unroll
  for (int mt = 0; mt < 2; ++mt)
    #pragma unroll
    for (int r = 0; r < 4; ++r){
      int m = mt*16 + q*4 + r;
      #pragma unroll
      for (int tj = 0; tj < 2; ++tj){
        int j = wv*32 + tj*16 + lc;
        __builtin_nontemporal_store(hreg[mt][r][tj],
            &h_out[(((long)dir*128 + bat)*32 + m)*256 + j]);
      }
    }
}

// ---------------------------------------------------------------------------
// h_avg = 0.5(h_f + h_b); cos = |q.d|/(|q||d|); softmax over 31 docs.
// ---------------------------------------------------------------------------
__global__ void finalize(const float* __restrict__ h_out, float* __restrict__ out){
  __shared__ float hav[32*256];
  __shared__ float dotl[32], sql[32];
  const int bat = blockIdx.x;
  const int tid = threadIdx.x;
  const float* hf = h_out + (long)bat*8192;
  const float* hb = h_out + (long)(128 + bat)*8192;
  for (int i = tid; i < 8192; i += 256) hav[i] = 0.5f*(hf[i] + hb[i]);
  __syncthreads();
  const int lane = tid & 63, wv = tid >> 6;
  for (int n = wv; n < 32; n += 4){
    float s1 = 0.f, s2 = 0.f;
    for (int j = lane; j < 256; j += 64){
      float a  = hav[n*256 + j];
      float qv = hav[j];
      s1 += a*qv; s2 += a*a;
    }
    #pragma unroll
    for (int off = 32; off; off >>= 1){
      s1 += __shfl_down(s1, off);
      s2 += __shfl_down(s2, off);
    }
    if (lane == 0){ dotl[n] = s1; sql[n] = s2; }
  }
  __syncthreads();
  if (wv == 0){
    float cosv = -1e30f;
    if (lane < 31)
      cosv = fabsf(dotl[lane+1]) / (sqrtf(sql[0]) * sqrtf(sql[lane+1]));
    float mx = cosv;
    #pragma unroll
    for (int off = 32; off; off >>= 1) mx = fmaxf(mx, __shfl_xor(mx, off));
    float e = (lane < 31) ? __expf(cosv - mx) : 0.f;
    float sum = e;
    #pragma unroll
    for (int off = 32; off; off >>= 1) sum += __shfl_xor(sum, off);
    if (lane < 31) out[bat*31 + lane] = e / sum;
  }
}

extern "C" void kernel_launch(void* const* d_in, const int* in_sizes, int n_in,
                              void* d_out, int out_size, void* d_ws, size_t ws_size,
                              hipStream_t stream) {
  const int*   inputs = (const int*)  d_in[0];
  const float* emb    = (const float*)d_in[1];
  const float* k_f    = (const float*)d_in[2];
  const float* rk_f   = (const float*)d_in[3];
  const float* b_f    = (const float*)d_in[4];
  const float* wci_f  = (const float*)d_in[5];
  const float* wcf_f  = (const float*)d_in[6];
  const float* wco_f  = (const float*)d_in[7];
  const float* k_b    = (const float*)d_in[8];
  const float* rk_b   = (const float*)d_in[9];
  const float* b_b    = (const float*)d_in[10];
  const float* wci_b  = (const float*)d_in[11];
  const float* wcf_b  = (const float*)d_in[12];
  const float* wco_b  = (const float*)d_in[13];

  unsigned short* rkp  = (unsigned short*)d_ws;
  unsigned short* kp   = (unsigned short*)((char*)d_ws + OFF_KP);
  _Float16*       xzp  = (_Float16*)     ((char*)d_ws + OFF_XZ);
  float*          hout = (float*)        ((char*)d_ws + OFF_HOUT);

  prepack<<<(RKP_SHORTS + KP_SHORTS)/256, 256, 0, stream>>>(k_f, rk_f, k_b, rk_b, rkp, kp);
  xzgemm <<<128*2*5, 512, 0, stream>>>(inputs, emb, kp, b_f, b_b, xzp);
  lstm_rec<<<256, 512, 0, stream>>>(inputs, xzp, rkp,
                                    wci_f, wcf_f, wco_f,
                                    wci_b, wcf_b, wco_b, hout);
  finalize<<<128, 256, 0, stream>>>(hout, (float*)d_out);
}